// Round 1
// baseline (67.857 us; speedup 1.0000x reference)
//
#include <hip/hip_runtime.h>
#include <math.h>

#define NN   96
#define NPOS (96*96)   // 9216
#define BB   32
#define KV   1024
#define KA   2048
#define KCH  256
#define NCHV (KV/KCH)  // 4
#define NCHA (KA/KCH)  // 8
#define PTILE 256
#define NBLK_V (NCHV*(NPOS/PTILE))   // 4*36 = 144
#define NBLK_A (NCHA*(NPOS/PTILE))   // 8*36 = 288
#define NBLK_TOTAL (NBLK_V + NBLK_A) // 432

// ws layout (floats):
#define PARTV_OFF 0
#define PARTA_OFF (NCHV*BB*NPOS)
#define CPT_OFF   (PARTA_OFF + NCHA*BB*NPOS)
// total: (4+8)*32*9216 + 6*9216 floats = ~14.4 MB

// ---------------- nb: separable DoG convolutions ----------------
// nb_f = l_ex * G_ex @ act @ G_ex^T - l_in * G_in @ act @ G_in^T
// One block per (field, ex/in) component; writes signed-scaled cpt[c][9216].
__global__ __launch_bounds__(1024) void nb_kernel(
    const float* __restrict__ na_v, const float* __restrict__ na_a,
    const float* __restrict__ na_m, float* __restrict__ ws)
{
    __shared__ float G[96][100];    // padded rows to dodge bank conflicts
    __shared__ float buf[96][100];  // act, then T1^T
    const int c = blockIdx.x;       // 0..5
    float l, s;
    if      (c == 0) { l =  1.60f; s = 3.5f;  }
    else if (c == 1) { l = -1.23f; s = 6.3f;  }
    else if (c == 2) { l =  1.00f; s = 5.3f;  }
    else if (c == 3) { l = -0.80f; s = 11.8f; }
    else if (c == 4) { l =  3.80f; s = 3.5f;  }
    else             { l = -3.30f; s = 6.2f;  }
    const float s2 = s * s;
    const int f = c >> 1;
    const float* act = (f == 0) ? na_v : (f == 1) ? na_a : na_m;
    const int tid = threadIdx.x;

    for (int idx = tid; idx < 9216; idx += 1024) {
        int j = idx / 96, k = idx % 96;
        int d = abs(j - k); d = min(d, 96 - d);
        G[j][k]   = __expf(-0.5f * (float)(d * d) * s2);
        buf[j][k] = act[idx];
    }
    __syncthreads();

    const int hg = tid >> 5, jg = tid & 31;   // 32 x 32 thread grid
    const int h0 = hg * 3, j0 = jg * 3;

    // stage 1: T1[h,j] = sum_k act[h,k] * G[j,k]
    float t1[3][3] = {};
    for (int k0 = 0; k0 < 96; k0 += 4) {
        float4 av[3], gv[3];
        #pragma unroll
        for (int r = 0; r < 3; r++) {
            av[r] = *(const float4*)&buf[h0 + r][k0];
            gv[r] = *(const float4*)&G[j0 + r][k0];
        }
        #pragma unroll
        for (int hh = 0; hh < 3; hh++)
            #pragma unroll
            for (int jj = 0; jj < 3; jj++)
                t1[hh][jj] += av[hh].x * gv[jj].x + av[hh].y * gv[jj].y
                            + av[hh].z * gv[jj].z + av[hh].w * gv[jj].w;
    }
    __syncthreads();
    // write T1 transposed: buf[j][h] = T1[h][j]
    #pragma unroll
    for (int hh = 0; hh < 3; hh++)
        #pragma unroll
        for (int jj = 0; jj < 3; jj++)
            buf[j0 + jj][h0 + hh] = t1[hh][jj];
    __syncthreads();

    // stage 2: out[i,j] = sum_h G[i,h] * T1[h,j]
    const int i0 = hg * 3;
    float o[3][3] = {};
    for (int hb = 0; hb < 96; hb += 4) {
        float4 gv[3], bv[3];
        #pragma unroll
        for (int r = 0; r < 3; r++) {
            gv[r] = *(const float4*)&G[i0 + r][hb];
            bv[r] = *(const float4*)&buf[j0 + r][hb];
        }
        #pragma unroll
        for (int ii = 0; ii < 3; ii++)
            #pragma unroll
            for (int jj = 0; jj < 3; jj++)
                o[ii][jj] += gv[ii].x * bv[jj].x + gv[ii].y * bv[jj].y
                           + gv[ii].z * bv[jj].z + gv[ii].w * bv[jj].w;
    }
    float* cpt = ws + CPT_OFF + c * NPOS;
    #pragma unroll
    for (int ii = 0; ii < 3; ii++)
        #pragma unroll
        for (int jj = 0; jj < 3; jj++)
            cpt[(i0 + ii) * 96 + (j0 + jj)] = l * o[ii][jj];
}

// ---------------- ext GEMMs: C[b,p] = sum_k src[b,k] * rf[p,k] ----------------
// One thread owns one position p and all 32 batch accumulators.
// video/audio chunk staged in LDS k-major; rf streamed from global (read-once).
__global__ __launch_bounds__(256) void ext_kernel(
    const float* __restrict__ video, const float* __restrict__ audio,
    const float* __restrict__ rf_v, const float* __restrict__ rf_a,
    float* __restrict__ ws)
{
    __shared__ float A[KCH][BB];   // 32 KB, A[kk][b]
    const int bid = blockIdx.x;
    const float* src; const float* rf; float* part; int K;
    int chunk, ptile;
    if (bid < NBLK_V) {
        chunk = bid / 36; ptile = bid % 36;
        src = video; rf = rf_v; K = KV;
        part = ws + PARTV_OFF + chunk * (BB * NPOS);
    } else {
        int idx = bid - NBLK_V;
        chunk = idx / 36; ptile = idx % 36;
        src = audio; rf = rf_a; K = KA;
        part = ws + PARTA_OFF + chunk * (BB * NPOS);
    }
    const int kbase = chunk * KCH;
    const int tid = threadIdx.x;

    // stage A: each thread loads 32 consecutive k of one batch row
    {
        const int b = tid & 31;
        const int kk0 = (tid >> 5) * 32;
        const float* sp = src + (size_t)b * K + kbase + kk0;
        #pragma unroll
        for (int q = 0; q < 32; q++) A[kk0 + q][b] = sp[q];
    }
    __syncthreads();

    const int p = ptile * PTILE + tid;
    const float* bp = rf + (size_t)p * K + kbase;
    float acc[BB];
    #pragma unroll
    for (int b = 0; b < BB; b++) acc[b] = 0.f;

    #pragma unroll 2
    for (int kk = 0; kk < KCH; kk += 8) {
        float4 b0 = *(const float4*)&bp[kk];
        float4 b1 = *(const float4*)&bp[kk + 4];
        float bs[8] = {b0.x, b0.y, b0.z, b0.w, b1.x, b1.y, b1.z, b1.w};
        #pragma unroll
        for (int j = 0; j < 8; j++) {
            const float bk = bs[j];
            #pragma unroll
            for (int b4 = 0; b4 < 8; b4++) {
                float4 av = *(const float4*)&A[kk + j][b4 * 4];
                acc[b4 * 4 + 0] += av.x * bk;
                acc[b4 * 4 + 1] += av.y * bk;
                acc[b4 * 4 + 2] += av.z * bk;
                acc[b4 * 4 + 3] += av.w * bk;
            }
        }
    }

    #pragma unroll
    for (int b = 0; b < BB; b++) part[(size_t)b * NPOS + p] = acc[b];
}

// ---------------- combine: reduce partials + sigmoid dynamics ----------------
__global__ __launch_bounds__(256) void combine_kernel(
    const float* __restrict__ na_v, const float* __restrict__ na_a,
    const float* __restrict__ na_m, const float* __restrict__ ws,
    float* __restrict__ out)
{
    const int idx = blockIdx.x * 256 + threadIdx.x;
    if (idx >= BB * NPOS) return;
    const int b = idx / NPOS, p = idx % NPOS;
    const float* pv  = ws + PARTV_OFF;
    const float* pa  = ws + PARTA_OFF;
    const float* cpt = ws + CPT_OFF;

    float ext_v = 0.f, ext_a = 0.f;
    #pragma unroll
    for (int c = 0; c < NCHV; c++) ext_v += pv[c * (BB * NPOS) + b * NPOS + p];
    #pragma unroll
    for (int c = 0; c < NCHA; c++) ext_a += pa[c * (BB * NPOS) + b * NPOS + p];

    const float nb_v = cpt[0 * NPOS + p] + cpt[1 * NPOS + p];
    const float nb_a = cpt[2 * NPOS + p] + cpt[3 * NPOS + p];
    const float nb_m = cpt[4 * NPOS + p] + cpt[5 * NPOS + p];
    const float nv = na_v[p], na = na_a[p], nm = na_m[p];

    const float xv = (ext_v + nb_v - 3.0f + nm) * 0.3f;
    const float nav_new = nv * (2.f / 3.f) + (1.f / 3.f) / (1.f + __expf(-xv));
    const float xa = (ext_a + nb_a - 3.0f + nm) * 0.3f;
    const float naa_new = na * (2.f / 3.f) + (1.f / 3.f) / (1.f + __expf(-xa));
    const float xm = (7.0f * nav_new + 3.0f * naa_new + nb_m - 3.0f) * 0.3f;
    out[idx] = nm * (2.f / 3.f) + (1.f / 3.f) / (1.f + __expf(-xm));
}

extern "C" void kernel_launch(void* const* d_in, const int* in_sizes, int n_in,
                              void* d_out, int out_size, void* d_ws, size_t ws_size,
                              hipStream_t stream) {
    const float* video = (const float*)d_in[0];
    const float* audio = (const float*)d_in[1];
    const float* rf_v  = (const float*)d_in[2];
    const float* rf_a  = (const float*)d_in[3];
    const float* na_v  = (const float*)d_in[4];
    const float* na_a  = (const float*)d_in[5];
    const float* na_m  = (const float*)d_in[6];
    float* ws  = (float*)d_ws;
    float* out = (float*)d_out;

    nb_kernel<<<6, 1024, 0, stream>>>(na_v, na_a, na_m, ws);
    ext_kernel<<<NBLK_TOTAL, 256, 0, stream>>>(video, audio, rf_v, rf_a, ws);
    combine_kernel<<<(BB * NPOS + 255) / 256, 256, 0, stream>>>(na_v, na_a, na_m, ws, out);
}